// Round 4
// baseline (180.010 us; speedup 1.0000x reference)
//
#include <hip/hip_runtime.h>
#include <hip/hip_bf16.h>
#include <hip/hip_cooperative_groups.h>

namespace cg = cooperative_groups;

#define EPSW 1e-6f

typedef __attribute__((ext_vector_type(4))) float floatx4;
typedef __attribute__((ext_vector_type(8))) short shortx8;   // 8 bf16 (4 VGPRs)

// round-to-nearest-even float -> bf16 bits (finite inputs)
__device__ __forceinline__ unsigned short f2bf(float f) {
    unsigned int u = __float_as_uint(f);
    u = (u + 0x7fffu + ((u >> 16) & 1u)) >> 16;
    return (unsigned short)u;
}

// ---------------------------------------------------------------------------
// Single cooperative kernel, 256 blocks x 256 threads (1 block/CU).
// Phase A: x (2048x2000 fp32) -> xt bf16 [kg][row][8] (K padded to 2048);
//          W -> wt bf16 [kg][h][8] (block bid converts kg=bid, even spread);
//          block 255 additionally builds A and Mt=(A@A)^T.
// Phase B: z = x @ W^T via MFMA, barrier-free streaming from xt/wt
//          (xt is L3-resident after phase A -> reads hit Infinity Cache).
// Phase C: y = M.z + bias  (apply_M of round 2, unchanged math).
// grid.sync() provides the cross-XCD fence + barrier between phases.
// ---------------------------------------------------------------------------
__global__ __launch_bounds__(256) void fused(
        const float* __restrict__ x, const float* __restrict__ W,
        const int* __restrict__ ei, const float* __restrict__ ew,
        const float* __restrict__ bias,
        unsigned short* __restrict__ xt, unsigned short* __restrict__ wt,
        float* __restrict__ Mt, float* __restrict__ z, float* __restrict__ y) {
    __shared__ __align__(16) unsigned char smem[50688];
    const int bid = blockIdx.x;
    const int t   = threadIdx.x;
    cg::grid_group grid = cg::this_grid();

    // ===================== Phase A =====================
    {
        unsigned short(*tile)[264] = (unsigned short(*)[264])smem;  // 33792 B
        const int rb   = (bid >> 3) * 64;      // 32 row-tiles
        const int kgb  = (bid & 7) * 32;       // 8 kg-tiles
        const int kbas = kgb * 8;
        // coalesced fp32 reads -> bf16 LDS tile (64 rows x 256 k)
#pragma unroll
        for (int i = 0; i < 16; ++i) {
            const int idx = i * 256 + t;
            const int r   = idx >> 6;          // 0..63
            const int kc  = (idx & 63) * 4;    // 0..252
            const int k   = kbas + kc;
            floatx4 v = (floatx4){0.f, 0.f, 0.f, 0.f};
            if (k < 2000)
                v = *(const floatx4*)(x + (size_t)(rb + r) * 2000 + k);
            tile[r][kc + 0] = f2bf(v.x);
            tile[r][kc + 1] = f2bf(v.y);
            tile[r][kc + 2] = f2bf(v.z);
            tile[r][kc + 3] = f2bf(v.w);
        }
        // wt: block bid converts granule column kg = bid for all h
        if (t < 128) {
            const int kg = bid, h = t, k = kg * 8;
            floatx4 v0 = (floatx4){0.f, 0.f, 0.f, 0.f};
            floatx4 v1 = (floatx4){0.f, 0.f, 0.f, 0.f};
            if (k < 2000) {  // kg<=249 -> whole granule valid
                v0 = *(const floatx4*)(W + (size_t)h * 2000 + k);
                v1 = *(const floatx4*)(W + (size_t)h * 2000 + k + 4);
            }
            unsigned short* p = wt + ((size_t)kg * 128 + h) * 8;
            p[0] = f2bf(v0.x); p[1] = f2bf(v0.y); p[2] = f2bf(v0.z); p[3] = f2bf(v0.w);
            p[4] = f2bf(v1.x); p[5] = f2bf(v1.y); p[6] = f2bf(v1.z); p[7] = f2bf(v1.w);
        }
        __syncthreads();
        // 16B granules out, coalesced over rows
#pragma unroll
        for (int i = 0; i < 8; ++i) {
            const int kg_l = i * 4 + (t >> 6);  // wave-uniform
            const int r    = t & 63;
            const shortx8 g = *(const shortx8*)&tile[r][kg_l * 8];
            *(shortx8*)(xt + ((size_t)(kgb + kg_l) * 2048 + rb + r) * 8) = g;
        }
        if (bid == 255) {
            float* A    = (float*)(smem + 33792);   // 4096 f (disjoint from tile)
            float* deg  = A + 4096;
            float* dinv = deg + 64;
            if (t < 64) deg[t] = 1.0f;              // self-loop pre-added
            for (int i = t; i < 4096; i += 256) A[i] = 0.0f;
            __syncthreads();
            const int* src = ei;
            const int* dst = ei + 4096;
            for (int e = t; e < 4096; e += 256) {
                float w = ew[e];
                w = (w <= 0.0f) ? EPSW : w;
                atomicAdd(&deg[dst[e]], w);
            }
            __syncthreads();
            if (t < 64) dinv[t] = 1.0f / sqrtf(deg[t]);
            __syncthreads();
            for (int e = t; e < 4096; e += 256) {
                float w = ew[e];
                w = (w <= 0.0f) ? EPSW : w;
                const int s = src[e], d = dst[e];
                atomicAdd(&A[d * 64 + s], dinv[s] * w * dinv[d]);
            }
            if (t < 64) atomicAdd(&A[t * 64 + t], dinv[t] * dinv[t]);
            __syncthreads();
            // Mt[c][n] = (A@A)[n][c]
#pragma unroll
            for (int i = 0; i < 16; ++i) {
                const int idx = i * 256 + t;
                const int n = idx >> 6, c = idx & 63;
                float s = 0.0f;
#pragma unroll 8
                for (int k = 0; k < 64; ++k) s += A[n * 64 + k] * A[k * 64 + c];
                Mt[c * 64 + n] = s;
            }
        }
    }
    grid.sync();

    // ===================== Phase B: gemm =====================
    {
        const int wave = t >> 6, lane = t & 63;
        const int m = lane & 15, q = lane >> 4;
        const int rbase = (bid >> 1) * 16;               // 128 row-tiles
        const int hbase = (bid & 1) * 64 + wave * 16;    // 2 h-halves x 4 waves
        const shortx8* Ag = (const shortx8*)xt;
        const shortx8* Bg = (const shortx8*)wt;
        int ga = q * 2048 + rbase + m;   // +8192 per kt
        int gb = q * 128 + hbase + m;    // +512  per kt
        floatx4 acc0 = (floatx4){0.f, 0.f, 0.f, 0.f};
        floatx4 acc1 = (floatx4){0.f, 0.f, 0.f, 0.f};
#pragma unroll 4
        for (int kt = 0; kt < 64; kt += 2) {
            const shortx8 a0 = Ag[ga];
            const shortx8 b0 = Bg[gb];
            const shortx8 a1 = Ag[ga + 8192];
            const shortx8 b1 = Bg[gb + 512];
            acc0 = __builtin_amdgcn_mfma_f32_16x16x32_bf16(a0, b0, acc0, 0, 0, 0);
            acc1 = __builtin_amdgcn_mfma_f32_16x16x32_bf16(a1, b1, acc1, 0, 0, 0);
            ga += 16384; gb += 1024;
        }
#pragma unroll
        for (int v = 0; v < 4; ++v)
            z[(size_t)(rbase + q * 4 + v) * 128 + hbase + m] = acc0[v] + acc1[v];
    }
    grid.sync();

    // ===================== Phase C: apply M =====================
    {
        float* Ms       = (float*)smem;                     // 16384 B
        float(*zs)[16]  = (float(*)[16])(smem + 16384);     // 4096 B
        const int b  = bid >> 3;
        const int hc = bid & 7;
#pragma unroll
        for (int i = 0; i < 16; ++i) Ms[i * 256 + t] = Mt[i * 256 + t];
#pragma unroll
        for (int i = 0; i < 4; ++i) {
            const int idx = i * 256 + t;
            const int mr = idx >> 4, hh = idx & 15;
            zs[mr][hh] = z[(size_t)(b * 64 + mr) * 128 + hc * 16 + hh];
        }
        __syncthreads();
        const int h  = t & 15;
        const int n0 = (t >> 4) * 4;
        const float bv = bias[hc * 16 + h];
        float s0 = bv, s1 = bv, s2 = bv, s3 = bv;
#pragma unroll
        for (int mm = 0; mm < 64; ++mm) {
            const float zv = zs[mm][h];
            s0 += Ms[mm * 64 + n0 + 0] * zv;
            s1 += Ms[mm * 64 + n0 + 1] * zv;
            s2 += Ms[mm * 64 + n0 + 2] * zv;
            s3 += Ms[mm * 64 + n0 + 3] * zv;
        }
        float* yp = y + (size_t)b * 8192 + (size_t)n0 * 128 + hc * 16 + h;
        yp[0]   = s0;
        yp[128] = s1;
        yp[256] = s2;
        yp[384] = s3;
    }
}

extern "C" void kernel_launch(void* const* d_in, const int* in_sizes, int n_in,
                              void* d_out, int out_size, void* d_ws, size_t ws_size,
                              hipStream_t stream) {
    const float* x    = (const float*)d_in[0];   // (2048, 2000) fp32
    const int*   ei   = (const int*)d_in[1];     // (2, 4096)
    const float* ew   = (const float*)d_in[2];   // (4096,)
    const float* W    = (const float*)d_in[3];   // (128, 2000) fp32
    const float* bias = (const float*)d_in[4];   // (128,)
    float* y = (float*)d_out;                    // (32, 64, 128) fp32

    float* z  = (float*)d_ws;                    // 262144 f (1 MB)
    float* Mt = z + 262144;                      // 4096 f
    unsigned short* xt = (unsigned short*)(Mt + 4096);   // 256*2048*8 bf16 (8 MB)
    unsigned short* wt = xt + 4194304;                   // 256*128*8 bf16 (512 KB)

    void* args[] = {(void*)&x, (void*)&W, (void*)&ei, (void*)&ew, (void*)&bias,
                    (void*)&xt, (void*)&wt, (void*)&Mt, (void*)&z, (void*)&y};
    hipLaunchCooperativeKernel((const void*)fused, dim3(256), dim3(256),
                               args, 0, stream);
}

// Round 5
// 102.457 us; speedup vs baseline: 1.7569x; 1.7569x over previous
//
#include <hip/hip_runtime.h>
#include <hip/hip_bf16.h>

#define EPSW 1e-6f

typedef __attribute__((ext_vector_type(4))) float floatx4;
typedef __attribute__((ext_vector_type(8))) short shortx8;   // 8 bf16 (4 VGPRs)

// round-to-nearest-even float -> bf16 bits (finite inputs)
__device__ __forceinline__ unsigned short f2bf(float f) {
    unsigned int u = __float_as_uint(f);
    u = (u + 0x7fffu + ((u >> 16) & 1u)) >> 16;
    return (unsigned short)u;
}

// ---------------------------------------------------------------------------
// prep: 273 blocks x 256 threads (identical to round-2 known-good version).
//   blocks 0..255 : xt transpose. x (2048 rows x 2000 K fp32) -> xt bf16 in
//                   MFMA-A-fragment layout [kg][row][8], kg = k/8, K padded
//                   to 2048 (kg 0..255) with zeros. Block = 64 rows x 32 kg.
//   blocks 256..271: wt transform. W (128 x 2000 fp32) -> wt bf16 [kg][h][8].
//   block 272     : A (normalized adjacency) and Mt = (A@A)^T.
// ---------------------------------------------------------------------------
__global__ __launch_bounds__(256) void prep(const float* __restrict__ x,
                                            const float* __restrict__ W,
                                            const int* __restrict__ ei,
                                            const float* __restrict__ ew,
                                            unsigned short* __restrict__ xt,
                                            unsigned short* __restrict__ wt,
                                            float* __restrict__ Mt) {
    __shared__ __align__(16) unsigned char smem[64 * 264 * 2];  // 33792 B
    const int bid = blockIdx.x;
    const int t   = threadIdx.x;

    if (bid < 256) {
        unsigned short(*tile)[264] = (unsigned short(*)[264])smem;  // +8 pad
        const int rb   = (bid >> 3) * 64;      // 32 row-tiles
        const int kgb  = (bid & 7) * 32;       // 8 kg-tiles
        const int kbas = kgb * 8;
#pragma unroll
        for (int i = 0; i < 16; ++i) {
            const int idx = i * 256 + t;
            const int r   = idx >> 6;          // 0..63
            const int kc  = (idx & 63) * 4;    // 0..252
            const int k   = kbas + kc;
            floatx4 v = (floatx4){0.f, 0.f, 0.f, 0.f};
            if (k < 2000)
                v = *(const floatx4*)(x + (size_t)(rb + r) * 2000 + k);
            tile[r][kc + 0] = f2bf(v.x);
            tile[r][kc + 1] = f2bf(v.y);
            tile[r][kc + 2] = f2bf(v.z);
            tile[r][kc + 3] = f2bf(v.w);
        }
        __syncthreads();
#pragma unroll
        for (int i = 0; i < 8; ++i) {
            const int kg_l = i * 4 + (t >> 6);  // wave-uniform
            const int r    = t & 63;
            const shortx8 g = *(const shortx8*)&tile[r][kg_l * 8];
            *(shortx8*)(xt + ((size_t)(kgb + kg_l) * 2048 + rb + r) * 8) = g;
        }
    } else if (bid < 272) {
#pragma unroll
        for (int i = 0; i < 8; ++i) {
            const int G  = (bid - 256) * 2048 + i * 256 + t;  // 0..32767
            const int kg = G >> 7;
            const int h  = G & 127;
            const int k  = kg * 8;
            floatx4 v0 = (floatx4){0.f, 0.f, 0.f, 0.f};
            floatx4 v1 = (floatx4){0.f, 0.f, 0.f, 0.f};
            if (k < 2000) {  // kg<=249 -> whole granule valid
                v0 = *(const floatx4*)(W + (size_t)h * 2000 + k);
                v1 = *(const floatx4*)(W + (size_t)h * 2000 + k + 4);
            }
            unsigned short* p = wt + ((size_t)kg * 128 + h) * 8;
            p[0] = f2bf(v0.x); p[1] = f2bf(v0.y); p[2] = f2bf(v0.z); p[3] = f2bf(v0.w);
            p[4] = f2bf(v1.x); p[5] = f2bf(v1.y); p[6] = f2bf(v1.z); p[7] = f2bf(v1.w);
        }
    } else {
        float* A    = (float*)smem;            // 4096 f
        float* deg  = (float*)(smem + 16384);
        float* dinv = deg + 64;
        if (t < 64) deg[t] = 1.0f;             // self-loop pre-added
        for (int i = t; i < 4096; i += 256) A[i] = 0.0f;
        __syncthreads();
        const int* src = ei;
        const int* dst = ei + 4096;
        for (int e = t; e < 4096; e += 256) {
            float w = ew[e];
            w = (w <= 0.0f) ? EPSW : w;
            atomicAdd(&deg[dst[e]], w);
        }
        __syncthreads();
        if (t < 64) dinv[t] = 1.0f / sqrtf(deg[t]);
        __syncthreads();
        for (int e = t; e < 4096; e += 256) {
            float w = ew[e];
            w = (w <= 0.0f) ? EPSW : w;
            const int s = src[e], d = dst[e];
            atomicAdd(&A[d * 64 + s], dinv[s] * w * dinv[d]);
        }
        if (t < 64) atomicAdd(&A[t * 64 + t], dinv[t] * dinv[t]);
        __syncthreads();
        // Mt[c][n] = (A@A)[n][c]
#pragma unroll
        for (int i = 0; i < 16; ++i) {
            const int idx = i * 256 + t;
            const int n = idx >> 6, c = idx & 63;
            float s = 0.0f;
#pragma unroll 8
            for (int k = 0; k < 64; ++k) s += A[n * 64 + k] * A[k * 64 + c];
            Mt[c * 64 + n] = s;
        }
    }
}

// ---------------------------------------------------------------------------
// gemm_apply: block (ht, b) computes z-tile[64 rows][16 h] for batch b and
// h-range ht*16..+16 over full K=2048 (padded), then applies M + bias and
// writes y. 512 threads = 8 waves: wave = (kh, rt); rt = row-tile of 16,
// kh = K-half (kg 0..127 / 128..255). 32 MFMA/wave; K-halves reduced via LDS.
// No z in global memory; 8 waves/CU = 2/SIMD for latency hiding.
// zs padded [64][17]: store addr = (rt*16+q*4+v)*17+m, q-stride 68 -> 4
// distinct banks (was 4-way conflict at stride 64).
// Apply-phase LDS reads: Ms addr mm*64+n (4 distinct banks x 16-lane
// broadcast), zs addr mm*17+h (16 lanes same address broadcast) - clean.
// ---------------------------------------------------------------------------
__global__ __launch_bounds__(512) void gemm_apply(
        const unsigned short* __restrict__ xt,
        const unsigned short* __restrict__ wt,
        const float* __restrict__ Mt,
        const float* __restrict__ bias,
        float* __restrict__ y) {
    __shared__ float Ms[4096];        // Mt linear: Ms[m*64+n] = M[n][m]
    __shared__ float zs[64][17];
    const int t    = threadIdx.x;
    const int wave = t >> 6, lane = t & 63;
    const int m = lane & 15, q = lane >> 4;
    const int ht = blockIdx.x;        // 0..7
    const int b  = blockIdx.y;        // 0..31
    const int rt = wave & 3, kh = wave >> 2;

    // stage M into LDS (completes during the MFMA loop's shadow)
    {
        const floatx4* Mg4 = (const floatx4*)Mt;
        floatx4* Ms4 = (floatx4*)Ms;
        Ms4[t]       = Mg4[t];
        Ms4[t + 512] = Mg4[t + 512];
    }

    const shortx8* Ag = (const shortx8*)xt;
    const shortx8* Bg = (const shortx8*)wt;
    int ga = (kh * 128 + q) * 2048 + b * 64 + rt * 16 + m;  // +8192 per kt
    int gb = (kh * 128 + q) * 128 + ht * 16 + m;            // +512 per kt

    floatx4 acc0 = (floatx4){0.f, 0.f, 0.f, 0.f};
    floatx4 acc1 = (floatx4){0.f, 0.f, 0.f, 0.f};
#pragma unroll 4
    for (int kt = 0; kt < 32; kt += 2) {
        const shortx8 a0 = Ag[ga];
        const shortx8 b0 = Bg[gb];
        const shortx8 a1 = Ag[ga + 8192];
        const shortx8 b1 = Bg[gb + 512];
        acc0 = __builtin_amdgcn_mfma_f32_16x16x32_bf16(a0, b0, acc0, 0, 0, 0);
        acc1 = __builtin_amdgcn_mfma_f32_16x16x32_bf16(a1, b1, acc1, 0, 0, 0);
        ga += 16384; gb += 1024;
    }
    acc0 += acc1;

    // K-half reduction into zs.  C/D layout: row = q*4+v, col = m.
    __syncthreads();   // also covers Ms stores
    if (kh == 0) {
#pragma unroll
        for (int v = 0; v < 4; ++v) zs[rt * 16 + q * 4 + v][m] = acc0[v];
    }
    __syncthreads();
    if (kh == 1) {
#pragma unroll
        for (int v = 0; v < 4; ++v) zs[rt * 16 + q * 4 + v][m] += acc0[v];
    }
    __syncthreads();

    // apply M + bias: 1024 outputs, 2 per thread (same h, n and n+32)
    {
        const int n0 = t >> 4;        // 0..31
        const int h  = t & 15;
        const float bv = bias[ht * 16 + h];
        float s0 = bv, s1 = bv;
#pragma unroll
        for (int mm = 0; mm < 64; ++mm) {
            const float zv = zs[mm][h];
            s0 += Ms[mm * 64 + n0]      * zv;
            s1 += Ms[mm * 64 + n0 + 32] * zv;
        }
        float* yp = y + (size_t)b * 8192 + ht * 16 + h;
        yp[(size_t)n0 * 128]        = s0;
        yp[(size_t)(n0 + 32) * 128] = s1;
    }
}

extern "C" void kernel_launch(void* const* d_in, const int* in_sizes, int n_in,
                              void* d_out, int out_size, void* d_ws, size_t ws_size,
                              hipStream_t stream) {
    const float* x    = (const float*)d_in[0];   // (2048, 2000) fp32
    const int*   ei   = (const int*)d_in[1];     // (2, 4096)
    const float* ew   = (const float*)d_in[2];   // (4096,)
    const float* W    = (const float*)d_in[3];   // (128, 2000) fp32
    const float* bias = (const float*)d_in[4];   // (128,)
    float* y = (float*)d_out;                    // (32, 64, 128) fp32

    float* Mt = (float*)d_ws;                    // 4096 f
    unsigned short* xt = (unsigned short*)(Mt + 4096);   // 256*2048*8 bf16 (8 MB)
    unsigned short* wt = xt + 4194304;                   // 256*128*8 bf16 (512 KB)

    prep<<<273, 256, 0, stream>>>(x, W, ei, ew, xt, wt, Mt);
    gemm_apply<<<dim3(8, 32), 512, 0, stream>>>(xt, wt, Mt, bias, y);
}